// Round 7
// baseline (534.021 us; speedup 1.0000x reference)
//
#include <hip/hip_runtime.h>
#include <math.h>

#define N_NODES 50000
#define N_EDGES 800000
#define D 128
#define E_DIM 16
#define DEPTH 3

typedef _Float16 half2_t __attribute__((ext_vector_type(2)));
typedef _Float16 half4_t __attribute__((ext_vector_type(4)));
typedef _Float16 half8_t __attribute__((ext_vector_type(8)));
typedef float floatx4 __attribute__((ext_vector_type(4)));

#if defined(__has_builtin)
#if __has_builtin(__builtin_amdgcn_fdot2)
#define FDOT2(a, b, c) __builtin_amdgcn_fdot2((a), (b), (c), false)
#endif
#endif
#ifndef FDOT2
static __device__ __forceinline__ float fdot2_sw(half2_t a, half2_t b, float c) {
    return fmaf((float)a.x, (float)b.x, fmaf((float)a.y, (float)b.y, c));
}
#define FDOT2(a, b, c) fdot2_sw((a), (b), (c))
#endif

// fire-and-forget global->LDS DMA, 4B/lane: lane l's 4B lands at ldsbase+4*l
#define GLOAD4(gp, lp)                                                  \
    __builtin_amdgcn_global_load_lds(                                   \
        (const __attribute__((address_space(1))) unsigned int*)(gp),    \
        (__attribute__((address_space(3))) unsigned int*)(lp), 4, 0, 0)

// ---------------- CSR build (by dst) ----------------

__global__ void k_scan1(const int* __restrict__ deg, int* __restrict__ out1,
                        int* __restrict__ bsum) {
    __shared__ int s[256];
    int t = threadIdx.x;
    int base = blockIdx.x * 1024;
    int v[4]; int sum = 0;
#pragma unroll
    for (int j = 0; j < 4; j++) {
        int idx = base + t * 4 + j;
        int x = (idx < N_NODES) ? deg[idx] : 0;
        v[j] = x; sum += x;
    }
    s[t] = sum;
    __syncthreads();
    for (int d2 = 1; d2 < 256; d2 <<= 1) {
        int val = (t >= d2) ? s[t - d2] : 0;
        __syncthreads();
        s[t] += val;
        __syncthreads();
    }
    int run = (t > 0) ? s[t - 1] : 0;
#pragma unroll
    for (int j = 0; j < 4; j++) {
        int idx = base + t * 4 + j;
        run += v[j];
        if (idx < N_NODES) out1[idx] = run;
    }
    if (t == 255) bsum[blockIdx.x] = s[255];
}

// adds block-sum prefix (computed inline: <=48 adds over L1-broadcast values)
__global__ void k_scanadd(int* __restrict__ off, const int* __restrict__ bsum1,
                          int* __restrict__ head) {
    int i = blockIdx.x * blockDim.x + threadIdx.x;
    if (i == 0) { off[0] = 0; head[0] = 0; }
    if (i < N_NODES) {
        int nb = i >> 10;
        int add = 0;
        for (int j = 0; j < nb; j++) add += bsum1[j];
        int v = off[i + 1] + add;
        off[i + 1] = v;
        if (i + 1 < N_NODES) head[i + 1] = v;
    }
}

// Scatter edges into dst-sorted order. sorted[pos] = src-row BYTE offset.
// e-attr rows permuted along (f32->f16 convert fused): k_agg reads e-attrs
// sequentially in te (round-6 win: removes one random-gather stream).
__global__ void k_scatter(const int* __restrict__ src, const int* __restrict__ dst,
                          int* __restrict__ head, int* __restrict__ sorted,
                          const float* __restrict__ ea, _Float16* __restrict__ ea_s) {
    int e = blockIdx.x * blockDim.x + threadIdx.x;
    if (e < N_EDGES) {
        int d = dst[e];
        int pos = atomicAdd(&head[d], 1);
        sorted[pos] = src[e] << 8;
        const float* ep = ea + (size_t)e * E_DIM;
        float4 a = *(const float4*)(ep);
        float4 b = *(const float4*)(ep + 4);
        float4 c = *(const float4*)(ep + 8);
        float4 f = *(const float4*)(ep + 12);
        half8_t lo = {(_Float16)a.x, (_Float16)a.y, (_Float16)a.z, (_Float16)a.w,
                      (_Float16)b.x, (_Float16)b.y, (_Float16)b.z, (_Float16)b.w};
        half8_t hi = {(_Float16)c.x, (_Float16)c.y, (_Float16)c.z, (_Float16)c.w,
                      (_Float16)f.x, (_Float16)f.y, (_Float16)f.z, (_Float16)f.w};
        _Float16* op = ea_s + (size_t)pos * E_DIM;
        *(half8_t*)op = lo;
        *(half8_t*)(op + 8) = hi;
    }
}

// ------- prep: x f16 convert + MFMA weight packing + We packing + dst hist ---

#define NB_X   3125    // N_NODES*D/8/256
#define NB_W   384     // 6*16384/256
#define NB_WE  12      // 3*1024 half2 / 256
#define NB_H   3125    // N_EDGES/256
#define NB_PRE (NB_X + NB_W + NB_WE)

__global__ void k_prep(const float* __restrict__ x,
                       const float* __restrict__ W1, const float* __restrict__ W2,
                       const float* __restrict__ WeAll, const int* __restrict__ dst,
                       _Float16* __restrict__ xh,
                       _Float16* __restrict__ Wp, _Float16* __restrict__ Weh,
                       int* __restrict__ deg) {
    int b = blockIdx.x;
    if (b < NB_X) {
        int i = b * 256 + threadIdx.x;
        int base = i * 8;
        float4 a = *(const float4*)(x + base);
        float4 c = *(const float4*)(x + base + 4);
        half8_t h = {(_Float16)a.x, (_Float16)a.y, (_Float16)a.z, (_Float16)a.w,
                     (_Float16)c.x, (_Float16)c.y, (_Float16)c.z, (_Float16)c.w};
        *(half8_t*)(xh + base) = h;
    } else if (b < NB_X + NB_W) {
        int t = (b - NB_X) * 256 + threadIdx.x;
        int j    = t & 7;
        int lane = (t >> 3) & 63;
        int nb   = (t >> 9) & 7;
        int kb   = (t >> 12) & 3;
        int mat  = t >> 14;
        int layer = mat >> 1, which = mat & 1;
        const float* Wsrc = (which ? W2 : W1) + (size_t)layer * D * D;
        int k = kb * 32 + (lane >> 4) * 8 + j;
        int n = nb * 16 + (lane & 15);
        Wp[t] = (_Float16)Wsrc[k * D + n];
    } else if (b < NB_PRE) {
        // pack We as half2 k-pairs, 64-lane layout: [layer][lane=0..63][kp=0..7][f=0..1]
        // lane owns feats 2*lane, 2*lane+1
        int t = (b - NB_X - NB_W) * 256 + threadIdx.x;  // 0..3071 (half2 index)
        int layer = t >> 10;
        int idx = t & 1023;
        int lane = idx >> 4, kp = (idx >> 1) & 7, f = idx & 1;
        const float* Wsrc = WeAll + (size_t)layer * E_DIM * D;
        half2_t v = {(_Float16)Wsrc[(2 * kp) * D + 2 * lane + f],
                     (_Float16)Wsrc[(2 * kp + 1) * D + 2 * lane + f]};
        *(half2_t*)(Weh + 2 * (size_t)t) = v;
    } else {
        int e = (b - NB_PRE) * 256 + threadIdx.x;
        if (e < N_EDGES) atomicAdd(&deg[dst[e]], 1);
    }
}

// ---------------- per-layer: aggregation (DMA-pipelined) ----------------
// Wave-private double-buffered global_load_lds pipeline. Per chunk of 16
// edges: 16 x-row DMAs (256B each, zero VGPR cost) + 2 e-attr DMAs into the
// spare buffer, then compute current chunk from LDS. 18 outstanding gathers
// per wave vs the ~2 the compiler sustains with VGPR-destined loads (rounds
// 1/4/5). No __syncthreads (wave-private LDS): sync is one inline
// s_waitcnt vmcnt(0) per chunk — next chunk's loads are issued AFTER it, so
// the counted-wait is trivially correct and the pipeline stays depth-2.
// Lane owns feats {2*lane, 2*lane+1}: flush is a plain store (no shfl).

#define CHUNK 16
#define WBUF  4608          // CHUNK*256 (x rows) + 512 (ea rows)
#define AGG_BLOCKS 1024
#define AGG_WAVES  (AGG_BLOCKS * 4)               // 4096
#define AGG_Q      (N_NODES / AGG_WAVES)          // 12
#define AGG_R      (N_NODES - AGG_Q * AGG_WAVES)  // 848

__global__ __launch_bounds__(256, 4) void k_agg(
    const _Float16* __restrict__ xb, const _Float16* __restrict__ ea_s,
    const int* __restrict__ sorted, const int* __restrict__ off,
    const _Float16* __restrict__ Wea_l, const float* __restrict__ be_l,
    const float* __restrict__ eps_ptr, _Float16* __restrict__ h0) {
    __shared__ __align__(16) char smem[4 * 2 * WBUF];   // 36864 B
    int wslot = threadIdx.x >> 6;
    int lane  = threadIdx.x & 63;
    int wid   = blockIdx.x * 4 + wslot;

    char* LX[2]; char* LEA[2];
    {
        char* my = smem + wslot * (2 * WBUF);
        LX[0] = my;            LEA[0] = my + 4096;
        LX[1] = my + WBUF;     LEA[1] = my + WBUF + 4096;
    }

    // per-lane We slice: feats 2*lane..2*lane+1, 8 k-pairs -> 16 half2 regs
    half2_t w2[8][2];
    {
        const _Float16* wp = Wea_l + lane * 32;
#pragma unroll
        for (int q = 0; q < 4; q++) {
            half8_t wv = *(const half8_t*)(wp + 8 * q);
#pragma unroll
            for (int r = 0; r < 4; r++) {
                int p = 4 * q + r;
                w2[p >> 1][p & 1] = half2_t{wv[2 * r], wv[2 * r + 1]};
            }
        }
    }
    float bev0, bev1;
    { float2 bb = *(const float2*)(be_l + 2 * lane); bev0 = bb.x; bev1 = bb.y; }
    float epsv = 1.0f + eps_ptr[0];

    int nstart = wid * AGG_Q + (wid < AGG_R ? wid : AGG_R);
    int ncnt   = AGG_Q + (wid < AGG_R ? 1 : 0);
    int nend   = nstart + ncnt;
    int t0   = __builtin_amdgcn_readfirstlane(off[nstart]);
    int tEnd = __builtin_amdgcn_readfirstlane(off[nend]);

    const char* xbb  = (const char*)xb;
    const char* easb = (const char*)ea_s;

    int nn = nstart;
    int tnext = __builtin_amdgcn_readfirstlane(off[nn + 1]);
    float a0 = 0.f, a1 = 0.f;
    half2_t xself = *(const half2_t*)(xb + (size_t)nn * D + 2 * lane);

    // leading empty nodes
    while (nn < nend && tnext == t0) {
        half2_t oh;
        oh[0] = (_Float16)(epsv * (float)xself[0]);
        oh[1] = (_Float16)(epsv * (float)xself[1]);
        *(half2_t*)(h0 + (size_t)nn * D + 2 * lane) = oh;
        nn++;
        if (nn < nend) {
            tnext = __builtin_amdgcn_readfirstlane(off[nn + 1]);
            xself = *(const half2_t*)(xb + (size_t)nn * D + 2 * lane);
        }
    }

    int nch = (tEnd - t0 + CHUNK - 1) / CHUNK;
    if (nch > 0) {
        auto ldsorted = [&](int j) -> int {
            int idx = t0 + j * CHUNK + (lane & 15);
            idx = idx < N_EDGES ? idx : N_EDGES - 1;
            return sorted[idx];
        };
        // prologue: chunk 0 into buf 0
        int sv = ldsorted(0);
        {
#pragma unroll
            for (int e = 0; e < CHUNK; e++) {
                int sx = __builtin_amdgcn_readlane(sv, e);
                GLOAD4(xbb + sx + 4 * lane, LX[0] + e * 256);
            }
            size_t eb = (size_t)t0 * 32;
            GLOAD4(easb + eb + 4 * lane, LEA[0]);
            GLOAD4(easb + eb + 256 + 4 * lane, LEA[0] + 256);
        }
        int svn = (nch > 1) ? ldsorted(1) : 0;

        for (int j = 0; j < nch; j++) {
            int b = j & 1;
            asm volatile("s_waitcnt vmcnt(0)" ::: "memory");
            __builtin_amdgcn_sched_barrier(0);
            if (j + 1 < nch) {                      // issue next chunk
                int nb2 = b ^ 1;
#pragma unroll
                for (int e = 0; e < CHUNK; e++) {
                    int sx = __builtin_amdgcn_readlane(svn, e);
                    GLOAD4(xbb + sx + 4 * lane, LX[nb2] + e * 256);
                }
                size_t eb = (size_t)(t0 + (j + 1) * CHUNK) * 32;
                GLOAD4(easb + eb + 4 * lane, LEA[nb2]);
                GLOAD4(easb + eb + 256 + 4 * lane, LEA[nb2] + 256);
                if (j + 2 < nch) svn = ldsorted(j + 2);
            }
            // compute chunk j
            int basee = t0 + j * CHUNK;
            int cnt = tEnd - basee; if (cnt > CHUNK) cnt = CHUNK;
            const char* lx = LX[b];
            const char* lea = LEA[b];
            for (int e = 0; e < cnt; e++) {
                half2_t xv = *(const half2_t*)(lx + e * 256 + 4 * lane);
                half8_t elo = *(const half8_t*)(lea + e * 32);
                half8_t ehi = *(const half8_t*)(lea + e * 32 + 16);
                float p0 = bev0, p1 = bev1;
#pragma unroll
                for (int kp = 0; kp < 4; kp++) {
                    half2_t e2 = half2_t{elo[2 * kp], elo[2 * kp + 1]};
                    p0 = FDOT2(e2, w2[kp][0], p0);
                    p1 = FDOT2(e2, w2[kp][1], p1);
                }
#pragma unroll
                for (int kp = 0; kp < 4; kp++) {
                    half2_t e2 = half2_t{ehi[2 * kp], ehi[2 * kp + 1]};
                    p0 = FDOT2(e2, w2[kp + 4][0], p0);
                    p1 = FDOT2(e2, w2[kp + 4][1], p1);
                }
                a0 += fmaxf((float)xv[0] + p0, 0.f);
                a1 += fmaxf((float)xv[1] + p1, 0.f);
                int te1 = basee + e + 1;
                if (te1 == tnext) {                 // node boundary: flush
                    do {
                        half2_t oh;
                        oh[0] = (_Float16)(fmaf(epsv, (float)xself[0], a0));
                        oh[1] = (_Float16)(fmaf(epsv, (float)xself[1], a1));
                        *(half2_t*)(h0 + (size_t)nn * D + 2 * lane) = oh;
                        a0 = 0.f; a1 = 0.f;
                        nn++;
                        if (nn < nend) {
                            tnext = __builtin_amdgcn_readfirstlane(off[nn + 1]);
                            xself = *(const half2_t*)(xb + (size_t)nn * D + 2 * lane);
                        } else { tnext = -1; break; }
                    } while (tnext == te1);         // consecutive empty nodes
                }
            }
        }
    }
}

// ---------------- per-layer: fused node MLP via MFMA f16 ----------------

template <bool LAST>
__global__ __launch_bounds__(256) void k_mlp(
    const _Float16* __restrict__ h0, const _Float16* __restrict__ W1p,
    const float* __restrict__ b1, const _Float16* __restrict__ W2p,
    const float* __restrict__ b2, float* __restrict__ outf,
    _Float16* __restrict__ outh) {
    __shared__ _Float16 sH[64 * 136];
    __shared__ _Float16 sG[64 * 136];
    int n0 = blockIdx.x * 64;
    int t = threadIdx.x;

    for (int cc = t; cc < 1024; cc += 256) {
        int row = cc >> 4, c4 = cc & 15;
        uint4 v = make_uint4(0, 0, 0, 0);
        if (n0 + row < N_NODES)
            v = *(const uint4*)(h0 + (size_t)(n0 + row) * D + c4 * 8);
        *(uint4*)&sH[row * 136 + c4 * 8] = v;
    }
    __syncthreads();

    int w = t >> 6, lane = t & 63, q = lane >> 4, r16 = lane & 15;
    int mrow = w * 16 + r16;

    floatx4 acc[8];
#pragma unroll
    for (int nb = 0; nb < 8; nb++) acc[nb] = floatx4{0.f, 0.f, 0.f, 0.f};
#pragma unroll
    for (int kb = 0; kb < 4; kb++) {
        half8_t av = *(const half8_t*)&sH[mrow * 136 + kb * 32 + q * 8];
#pragma unroll
        for (int nb = 0; nb < 8; nb++) {
            half8_t bv = *(const half8_t*)(W1p + (size_t)((kb * 8 + nb) * 64 + lane) * 8);
            acc[nb] = __builtin_amdgcn_mfma_f32_16x16x32_f16(av, bv, acc[nb], 0, 0, 0);
        }
    }
#pragma unroll
    for (int nb = 0; nb < 8; nb++) {
        int col = nb * 16 + r16;
        float bb = b1[col];
#pragma unroll
        for (int r = 0; r < 4; r++) {
            float v = acc[nb][r] + bb;
            float gl = 0.5f * v * (1.0f + erff(v * 0.70710678118654752f));
            sG[(w * 16 + q * 4 + r) * 136 + col] = (_Float16)gl;
        }
    }
    // wave w writes exactly the sG rows it reads below — no barrier needed

#pragma unroll
    for (int nb = 0; nb < 8; nb++) acc[nb] = floatx4{0.f, 0.f, 0.f, 0.f};
#pragma unroll
    for (int kb = 0; kb < 4; kb++) {
        half8_t av = *(const half8_t*)&sG[mrow * 136 + kb * 32 + q * 8];
#pragma unroll
        for (int nb = 0; nb < 8; nb++) {
            half8_t bv = *(const half8_t*)(W2p + (size_t)((kb * 8 + nb) * 64 + lane) * 8);
            acc[nb] = __builtin_amdgcn_mfma_f32_16x16x32_f16(av, bv, acc[nb], 0, 0, 0);
        }
    }
#pragma unroll
    for (int nb = 0; nb < 8; nb++) {
        int col = nb * 16 + r16;
        float bb = b2[col];
#pragma unroll
        for (int r = 0; r < 4; r++) {
            int n = n0 + w * 16 + q * 4 + r;
            if (n < N_NODES) {
                float v = acc[nb][r] + bb;
                if (LAST) outf[(size_t)n * D + col] = v;
                else      outh[(size_t)n * D + col] = (_Float16)v;
            }
        }
    }
}

// ---------------- launch ----------------

static inline size_t align_up(size_t v, size_t a) { return (v + a - 1) & ~(a - 1); }

extern "C" void kernel_launch(void* const* d_in, const int* in_sizes, int n_in,
                              void* d_out, int out_size, void* d_ws, size_t ws_size,
                              hipStream_t stream) {
    const float* x         = (const float*)d_in[0];
    const float* edge_attr = (const float*)d_in[1];
    const float* W1        = (const float*)d_in[2];
    const float* b1        = (const float*)d_in[3];
    const float* W2        = (const float*)d_in[4];
    const float* b2        = (const float*)d_in[5];
    const float* We        = (const float*)d_in[6];
    const float* be        = (const float*)d_in[7];
    const float* eps       = (const float*)d_in[8];
    const int*   src       = (const int*)d_in[9];
    const int*   dst       = ((const int*)d_in[9]) + N_EDGES;

    char* w = (char*)d_ws;
    int*  off    = (int*)w;  w += align_up((N_NODES + 1) * sizeof(int), 16);
    int*  deg    = (int*)w;  w += align_up(N_NODES * sizeof(int), 16);
    int*  head   = (int*)w;  w += align_up(N_NODES * sizeof(int), 16);
    int*  bsum   = (int*)w;  w += 256;
    int*  sorted = (int*)w;  w += align_up((size_t)N_EDGES * sizeof(int), 16);
    _Float16* xb0 = (_Float16*)w; w += (size_t)N_NODES * D * 2;
    _Float16* xb1 = (_Float16*)w; w += (size_t)N_NODES * D * 2;
    _Float16* h0b = (_Float16*)w; w += (size_t)N_NODES * D * 2;
    _Float16* ea_s = (_Float16*)w; w += (size_t)N_EDGES * E_DIM * 2 + 1024; // +pad for chunk overshoot
    _Float16* Wp  = (_Float16*)w; w += (size_t)6 * 16384 * 2;
    _Float16* Weh = (_Float16*)w; w += (size_t)3 * 2048 * 2;   // packed We (half2 pairs, 64-lane)

    // ---- CSR build + prep (hist merged into prep; ea convert fused in scatter)
    hipMemsetAsync(deg, 0, N_NODES * sizeof(int), stream);
    k_prep<<<NB_PRE + NB_H, 256, 0, stream>>>(
        x, W1, W2, We, dst, xb0, Wp, Weh, deg);
    int nb1 = (N_NODES + 1023) / 1024;
    k_scan1<<<nb1, 256, 0, stream>>>(deg, off + 1, bsum);
    k_scanadd<<<(N_NODES + 255) / 256, 256, 0, stream>>>(off, bsum, head);
    k_scatter<<<(N_EDGES + 255) / 256, 256, 0, stream>>>(
        src, dst, head, sorted, edge_attr, ea_s);

    // ---- 3 layers ----
    _Float16* xcur = xb0;
    _Float16* xnxt = xb1;
    for (int l = 0; l < DEPTH; l++) {
        k_agg<<<AGG_BLOCKS, 256, 0, stream>>>(
            xcur, ea_s, sorted, off,
            Weh + (size_t)l * 2048, be + (size_t)l * D, eps + l, h0b);
        const _Float16* W1p = Wp + (size_t)(l * 2 + 0) * 16384;
        const _Float16* W2p = Wp + (size_t)(l * 2 + 1) * 16384;
        if (l == DEPTH - 1) {
            k_mlp<true><<<(N_NODES + 63) / 64, 256, 0, stream>>>(
                h0b, W1p, b1 + (size_t)l * D, W2p, b2 + (size_t)l * D,
                (float*)d_out, nullptr);
        } else {
            k_mlp<false><<<(N_NODES + 63) / 64, 256, 0, stream>>>(
                h0b, W1p, b1 + (size_t)l * D, W2p, b2 + (size_t)l * D,
                nullptr, xnxt);
        }
        _Float16* tmp = xcur; xcur = xnxt; xnxt = tmp;
    }
}